// Round 6
// baseline (3057466.211 us; speedup 1.0000x reference)
//
#include <hip/hip_runtime.h>
#include <hip/hip_fp16.h>

#define T_STEPS 500
#define HBUF_STRIDE 40960   // per (g,buf): hi 16384 | lo 16384 | fp8 8192
#define F8_SCALE    32768.0f
#define F8_INV      3.0517578125e-05f   // 2^-15

typedef _Float16 half_t;
typedef __attribute__((ext_vector_type(8))) _Float16 half8;
typedef __attribute__((ext_vector_type(4))) float    f32x4;
typedef unsigned int       u32;
typedef unsigned long long u64;

// Persistent LSTM, dual-path exchange, hang-hardened.
//   grid = 128 x 512. group g = bid & 15 owns batch rows [16g,16g+16);
//   j = bid >> 4 owns hidden slice U0 = j*64 (gate cols gate*512+U0+u).
//   Weights in registers: fp16 hi + fp8-e4m3 residual*2^15 (3-term GEMM,
//   verified absmax 0.0 in round 3).
//   Exchange: FAST (group same-XCD per runtime HW_REG_XCC_ID check): sc0
//   stores/loads through the shared (write-through-L1 -> L2) cache, vmcnt
//   ordering, zero cache-maintenance ops. SLOW (cross-XCD): relaxed
//   agent-scope atomics (MALL-coherent). BAIL (handshake cap exceeded):
//   skip waits -> fast garbage finish instead of a container-killing hang.
// ws: flags[16][32] u32 @0; xcd words @2048; hbuf [16][2][40960] @4096.

__device__ __forceinline__ float sigmoid_fast(float v) {
    return 1.f / (1.f + __expf(-v));
}
__device__ __forceinline__ float tanh_fast(float v) {
    float a = fabsf(v);
    float e = __expf(-2.f * a);
    float t = (1.f - e) / (1.f + e);
    return copysignf(t, v);
}

// ---- sc0 ops: L1-bypass, coherent within one XCD's L2 ----
__device__ __forceinline__ u32 load_u32_sc0(const u32* p) {
    u32 v;
    asm volatile("global_load_dword %0, %1, off sc0\ns_waitcnt vmcnt(0)"
                 : "=v"(v) : "v"(p) : "memory");
    return v;
}
__device__ __forceinline__ f32x4 load_f32x4_sc0_async(const void* p) {
    f32x4 v;
    asm volatile("global_load_dwordx4 %0, %1, off sc0" : "=v"(v) : "v"(p));
    return v;
}
__device__ __forceinline__ void store_u64_sc0(void* p, u64 v) {
    asm volatile("global_store_dwordx2 %0, %1, off sc0" :: "v"(p), "v"(v) : "memory");
}
__device__ __forceinline__ void store_u32_sc0(void* p, u32 v) {
    asm volatile("global_store_dword %0, %1, off sc0" :: "v"(p), "v"(v) : "memory");
}
__device__ __forceinline__ void wait_vm0() {
    asm volatile("s_waitcnt vmcnt(0)" ::: "memory");
}

__global__ __launch_bounds__(512, 2) void lstm_persist(
    const float* __restrict__ x,     const float* __restrict__ w_ih,
    const float* __restrict__ w_hh,  const float* __restrict__ b_ih,
    const float* __restrict__ b_hh,  const float* __restrict__ w_lin,
    const float* __restrict__ b_lin, float* __restrict__ out,
    u32* flags, char* hbase)
{
    __shared__ __align__(16) char stageBuf[40960];   // hi | lo | fp8, linear
    __shared__ float gate_s[4][16][68];              // 16B-aligned float4 rows
    __shared__ float wb_s[4][64][2];                 // {w_ih, b_ih+b_hh}
    __shared__ float xall[T_STEPS * 16];             // x staged once (32 KB)
    __shared__ u32 modeSh;

    half8* ldsAhi = (half8*)stageBuf;
    half8* ldsAlo = (half8*)(stageBuf + 16384);
    long*  ldsA8  = (long*)(stageBuf + 32768);

    const int tid = threadIdx.x;
    const int bid = blockIdx.x;
    const int g   = bid & 15;
    const int j   = bid >> 4;
    const int U0  = j * 64;
    const int m0  = g * 16;

    const int wave = tid >> 6, lane = tid & 63;
    const int kg   = lane >> 4, l15 = lane & 15;
    const int gw   = wave >> 1;
    const int usub = (wave & 1) * 32;

    // ---- one-time: W_hh slice -> registers (fp16 hi + fp8 residual) ----
    half8 bw0[16], bw1[16];
    long  b80[16], b81[16];
    {
        const int col0 = gw * 512 + U0 + usub + l15;
        const int col1 = col0 + 16;
#pragma unroll
        for (int ks = 0; ks < 16; ++ks) {
            const float* p0 = w_hh + col0 * 512 + ks * 32 + kg * 8;
            const float* p1 = w_hh + col1 * 512 + ks * 32 + kg * 8;
            float v0[8], v1[8];
            *(float4*)(v0)     = *(const float4*)p0;
            *(float4*)(v0 + 4) = *(const float4*)(p0 + 4);
            *(float4*)(v1)     = *(const float4*)p1;
            *(float4*)(v1 + 4) = *(const float4*)(p1 + 4);
            half8 w0h, w1h; float r0[8], r1[8];
#pragma unroll
            for (int q = 0; q < 8; ++q) {
                half_t a = (half_t)v0[q]; w0h[q] = a; r0[q] = (v0[q] - (float)a) * F8_SCALE;
                half_t b = (half_t)v1[q]; w1h[q] = b; r1[q] = (v1[q] - (float)b) * F8_SCALE;
            }
            bw0[ks] = w0h; bw1[ks] = w1h;
            int lo = __builtin_amdgcn_cvt_pk_fp8_f32(r0[0], r0[1], 0, false);
            lo     = __builtin_amdgcn_cvt_pk_fp8_f32(r0[2], r0[3], lo, true);
            int hi = __builtin_amdgcn_cvt_pk_fp8_f32(r0[4], r0[5], 0, false);
            hi     = __builtin_amdgcn_cvt_pk_fp8_f32(r0[6], r0[7], hi, true);
            b80[ks] = (long)(u32)lo | ((long)hi << 32);
            lo = __builtin_amdgcn_cvt_pk_fp8_f32(r1[0], r1[1], 0, false);
            lo = __builtin_amdgcn_cvt_pk_fp8_f32(r1[2], r1[3], lo, true);
            hi = __builtin_amdgcn_cvt_pk_fp8_f32(r1[4], r1[5], 0, false);
            hi = __builtin_amdgcn_cvt_pk_fp8_f32(r1[6], r1[7], hi, true);
            b81[ks] = (long)(u32)lo | ((long)hi << 32);
        }
    }

    // ---- one-time: constants + x -> LDS ----
    if (tid < 256) {
        int gg = tid >> 6, ul = tid & 63;
        int col = gg * 512 + U0 + ul;
        wb_s[gg][ul][0] = w_ih[col];
        wb_s[gg][ul][1] = b_ih[col] + b_hh[col];
    }
    for (int i = tid; i < T_STEPS * 16; i += 512)
        xall[i] = x[(i >> 4) * 256 + m0 + (i & 15)];

    // ---- one-time: XCD-placement handshake (BOUNDED) -> mode select ----
    // mode: 1 = fast (same-XCD L2), 0 = slow (MALL atomics), 2 = bail (no waits)
    u32* gflags = flags + g * 32;
    if (tid == 0) {
        u32 xcc;
        asm volatile("s_getreg_b32 %0, hwreg(HW_REG_XCC_ID)" : "=s"(xcc));
        u64* xw = (u64*)(flags + 512) + g;
        __hip_atomic_fetch_or(xw, (u64)(0x8u | (xcc & 7u)) << (8 * j),
                              __ATOMIC_RELAXED, __HIP_MEMORY_SCOPE_AGENT);
        u64 v = 0; int it = 0;
        do {
            v = __hip_atomic_load(xw, __ATOMIC_RELAXED, __HIP_MEMORY_SCOPE_AGENT);
            __builtin_amdgcn_s_sleep(2);
        } while ((v & 0x0808080808080808ull) != 0x0808080808080808ull
                 && ++it < (1 << 20));
        u32 f;
        if ((v & 0x0808080808080808ull) != 0x0808080808080808ull) {
            f = 2;                                   // bail: co-residency broken
        } else {
            f = 1; u32 x0 = (u32)(v & 7);
#pragma unroll
            for (int q = 1; q < 8; ++q)
                if (((v >> (8 * q)) & 7) != x0) f = 0;
        }
        modeSh = f;
    }
    __syncthreads();
    const u32 mode = modeSh;
    const bool fast = (mode == 1);

    // ---- pointwise ownership: tid<256, 4 hidden units each ----
    const int pm  = tid >> 4;          // local batch row 0..15
    const int pu4 = (tid & 15) * 4;    // hidden unit base 0..60
    const int kbg = j * 8 + (pu4 >> 3);
    const int off_hi = kbg * 256 + pm * 16 + (pu4 & 7) * 2;  // u64-aligned
    const int off_8  = kbg * 128 + pm * 8  + (pu4 & 7);      // u32-aligned
    float c4[4] = {0.f, 0.f, 0.f, 0.f};
    float h4[4] = {0.f, 0.f, 0.f, 0.f};

    // ---- startup: zero buf[1] (h_{-1}=0) via the selected path ----
    {
        char* z = hbase + (g * 2 + 1) * HBUF_STRIDE;
        if (fast) {
#pragma unroll
            for (int r = 0; r < 10; ++r)
                store_u64_sc0(z + (r * 512 + tid) * 8, 0ull);
        } else {
#pragma unroll
            for (int r = 0; r < 10; ++r)
                __hip_atomic_store((u64*)z + r * 512 + tid, 0ull,
                                   __ATOMIC_RELAXED, __HIP_MEMORY_SCOPE_AGENT);
        }
    }
    wait_vm0();
    __syncthreads();
    if (tid == 0) {
        if (fast) store_u32_sc0(&gflags[j], 1u);
        else __hip_atomic_store(&gflags[j], 1u, __ATOMIC_RELAXED, __HIP_MEMORY_SCOPE_AGENT);
    }

    // ---- time loop ----
    for (int t = 0; t < T_STEPS; ++t) {
        const int wb = t & 1, rb = wb ^ 1;

        // 1. wait for h_{t-1} from all 8 members (BOUNDED: cap -> proceed)
        if (tid < 8 && mode != 2) {
            const u32 want = (u32)(t + 1);
            int it = 0;
            if (fast) {
                while (load_u32_sc0(&gflags[tid]) < want && ++it < (1 << 16))
                    __builtin_amdgcn_s_sleep(1);
            } else {
                while (__hip_atomic_load(&gflags[tid], __ATOMIC_RELAXED,
                                         __HIP_MEMORY_SCOPE_AGENT) < want
                       && ++it < (1 << 16))
                    __builtin_amdgcn_s_sleep(2);
            }
        }
        __syncthreads();

        // 2. stage h_{t-1} (40 KB) into LDS
        {
            const char* src = hbase + (g * 2 + rb) * HBUF_STRIDE;
            if (fast) {
                const char* p = src + tid * 16;
                f32x4 t0 = load_f32x4_sc0_async(p);
                f32x4 t1 = load_f32x4_sc0_async(p + 8192);
                f32x4 t2 = load_f32x4_sc0_async(p + 16384);
                f32x4 t3 = load_f32x4_sc0_async(p + 24576);
                f32x4 t4 = load_f32x4_sc0_async(p + 32768);
                wait_vm0();
                f32x4* dst = (f32x4*)stageBuf;
                dst[tid] = t0; dst[512 + tid] = t1; dst[1024 + tid] = t2;
                dst[1536 + tid] = t3; dst[2048 + tid] = t4;
            } else {
                const u64* s8 = (const u64*)src;
                u64* dst = (u64*)stageBuf;
#pragma unroll
                for (int r = 0; r < 10; ++r)
                    dst[r * 512 + tid] = __hip_atomic_load(s8 + r * 512 + tid,
                                            __ATOMIC_RELAXED, __HIP_MEMORY_SCOPE_AGENT);
            }
        }
        __syncthreads();

        // 3. GEMM: 3-term split precision, B in registers, A from LDS
        f32x4 acc0 = {0.f, 0.f, 0.f, 0.f};
        f32x4 acc1 = {0.f, 0.f, 0.f, 0.f};
        f32x4 c80  = {0.f, 0.f, 0.f, 0.f};
        f32x4 c81  = {0.f, 0.f, 0.f, 0.f};
#pragma unroll
        for (int ks = 0; ks < 16; ++ks) {
            const int ai = (ks * 4 + kg) * 16 + l15;
            half8 ahi = ldsAhi[ai];
            half8 alo = ldsAlo[ai];
            long  a8  = ldsA8[ai];
            acc0 = __builtin_amdgcn_mfma_f32_16x16x32_f16(ahi, bw0[ks], acc0, 0, 0, 0);
            acc1 = __builtin_amdgcn_mfma_f32_16x16x32_f16(ahi, bw1[ks], acc1, 0, 0, 0);
            acc0 = __builtin_amdgcn_mfma_f32_16x16x32_f16(alo, bw0[ks], acc0, 0, 0, 0);
            acc1 = __builtin_amdgcn_mfma_f32_16x16x32_f16(alo, bw1[ks], acc1, 0, 0, 0);
            c80  = __builtin_amdgcn_mfma_f32_16x16x32_fp8_fp8(a8, b80[ks], c80, 0, 0, 0);
            c81  = __builtin_amdgcn_mfma_f32_16x16x32_fp8_fp8(a8, b81[ks], c81, 0, 0, 0);
        }
#pragma unroll
        for (int e = 0; e < 4; ++e) {   // D: col=lane&15, row=(lane>>4)*4+e
            gate_s[gw][kg * 4 + e][usub + l15]      = acc0[e] + c80[e] * F8_INV;
            gate_s[gw][kg * 4 + e][usub + 16 + l15] = acc1[e] + c81[e] * F8_INV;
        }
        __syncthreads();

        // 4. pointwise + publish h_t
        if (tid < 256) {
            float xv = xall[t * 16 + pm];
            float sg[4][4];
#pragma unroll
            for (int gg2 = 0; gg2 < 4; ++gg2) {
                float4 a  = *(float4*)&gate_s[gg2][pm][pu4];
                float4 wA = *(float4*)&wb_s[gg2][pu4][0];
                float4 wB = *(float4*)&wb_s[gg2][pu4 + 2][0];
                sg[gg2][0] = a.x + xv * wA.x + wA.y;
                sg[gg2][1] = a.y + xv * wA.z + wA.w;
                sg[gg2][2] = a.z + xv * wB.x + wB.y;
                sg[gg2][3] = a.w + xv * wB.z + wB.w;
            }
#pragma unroll
            for (int q = 0; q < 4; ++q) {
                float ii = sigmoid_fast(sg[0][q]);
                float ff = sigmoid_fast(sg[1][q]);
                float gv = tanh_fast(sg[2][q]);
                float oo = sigmoid_fast(sg[3][q]);
                c4[q] = ff * c4[q] + ii * gv;
                h4[q] = oo * tanh_fast(c4[q]);
            }
            union { half_t h[4]; u64 u; } hiU, loU;
#pragma unroll
            for (int q = 0; q < 4; ++q) {
                half_t hh = (half_t)h4[q];
                hiU.h[q] = hh;
                loU.h[q] = (half_t)(h4[q] - (float)hh);
            }
            int f8 = __builtin_amdgcn_cvt_pk_fp8_f32(h4[0], h4[1], 0, false);
            f8     = __builtin_amdgcn_cvt_pk_fp8_f32(h4[2], h4[3], f8, true);

            char* wrb = hbase + (g * 2 + wb) * HBUF_STRIDE;
            if (fast) {
                store_u64_sc0(wrb + off_hi, hiU.u);
                store_u64_sc0(wrb + 16384 + off_hi, loU.u);
                store_u32_sc0(wrb + 32768 + off_8, (u32)f8);
            } else {
                __hip_atomic_store((u64*)(wrb + off_hi), hiU.u,
                                   __ATOMIC_RELAXED, __HIP_MEMORY_SCOPE_AGENT);
                __hip_atomic_store((u64*)(wrb + 16384 + off_hi), loU.u,
                                   __ATOMIC_RELAXED, __HIP_MEMORY_SCOPE_AGENT);
                __hip_atomic_store((u32*)(wrb + 32768 + off_8), (u32)f8,
                                   __ATOMIC_RELAXED, __HIP_MEMORY_SCOPE_AGENT);
            }
        }
        wait_vm0();          // own h stores acked by coherence point
        __syncthreads();     // all threads' stores acked
        if (tid == 0) {
            if (fast) store_u32_sc0(&gflags[j], (u32)(t + 2));
            else __hip_atomic_store(&gflags[j], (u32)(t + 2),
                                    __ATOMIC_RELAXED, __HIP_MEMORY_SCOPE_AGENT);
        }
    }

    // ---- output: out[b] = w_lin . h_499[b] + b_lin (h in registers) ----
    if (tid < 256) {
        float part = h4[0] * w_lin[U0 + pu4]     + h4[1] * w_lin[U0 + pu4 + 1]
                   + h4[2] * w_lin[U0 + pu4 + 2] + h4[3] * w_lin[U0 + pu4 + 3];
        part += __shfl_xor(part, 1, 64);
        part += __shfl_xor(part, 2, 64);
        part += __shfl_xor(part, 4, 64);
        part += __shfl_xor(part, 8, 64);
        if ((tid & 15) == 0) {
            float v = part;
            if (j == 0) v += b_lin[0];
            atomicAdd(out + m0 + pm, v);
        }
    }
}

extern "C" void kernel_launch(void* const* d_in, const int* in_sizes, int n_in,
                              void* d_out, int out_size, void* d_ws, size_t ws_size,
                              hipStream_t stream) {
    const float* x     = (const float*)d_in[0];
    const float* w_ih  = (const float*)d_in[1];
    const float* w_hh  = (const float*)d_in[2];
    const float* b_ih  = (const float*)d_in[3];
    const float* b_hh  = (const float*)d_in[4];
    const float* w_lin = (const float*)d_in[5];
    const float* b_lin = (const float*)d_in[6];
    float* out = (float*)d_out;

    u32*  flags = (u32*)d_ws;
    char* hbase = (char*)d_ws + 4096;

    hipMemsetAsync(d_out, 0, out_size * sizeof(float), stream);
    hipMemsetAsync(d_ws, 0, 4096, stream);

    hipLaunchKernelGGL(lstm_persist, dim3(128), dim3(512), 0, stream,
                       x, w_ih, w_hh, b_ih, b_hh, w_lin, b_lin, out, flags, hbase);
}

// Round 8
// 2262.600 us; speedup vs baseline: 1351.3065x; 1351.3065x over previous
//
#include <hip/hip_runtime.h>
#include <hip/hip_fp16.h>

#define T_STEPS 500
#define HBUF_STRIDE 40960   // per (g,buf): hi 16384 | lo 16384 | fp8 8192
#define F8_SCALE    32768.0f
#define F8_INV      3.0517578125e-05f   // 2^-15
#define POLL_CAP    4096

typedef _Float16 half_t;
typedef __attribute__((ext_vector_type(8))) _Float16 half8;
typedef __attribute__((ext_vector_type(4))) float    f32x4;
typedef unsigned int       u32;
typedef unsigned long long u64;

// Persistent LSTM, single MALL-coherent exchange path.
//   grid = 128 x 512. group g = bid & 15 owns batch rows [16g,16g+16);
//   j = bid >> 4 owns hidden slice U0 = j*64 (gate cols gate*512+U0+u).
//   Weights in registers: fp16 hi + fp8-e4m3 residual*2^15 (3-term GEMM,
//   verified absmax 0.0 in rounds 3 & 6).
//   ALL cross-block traffic uses explicit `sc0 sc1` (bypass L1+L2, served at
//   MALL): round 6 proved cache-resident spin lines go permanently stale
//   (flag never seen -> 65536-iter cap -> 6.1 ms/step); sc1 on every such
//   access removes the possibility. No fences/wbl2/inv anywhere. Bounded
//   spins retained so any residual visibility failure ends in a fast
//   diagnosable absmax-fail, not a hang.
// ws: flags[16][32] u32 @0 (memset 0 each call); hbuf [16][2][40960] @4096.

__device__ __forceinline__ float sigmoid_fast(float v) {
    return 1.f / (1.f + __expf(-v));
}
__device__ __forceinline__ float tanh_fast(float v) {
    float a = fabsf(v);
    float e = __expf(-2.f * a);
    float t = (1.f - e) / (1.f + e);
    return copysignf(t, v);
}

// ---- MALL-coherent ops: sc0 sc1 = bypass L1 and L2 ----
__device__ __forceinline__ u32 load_u32_cc(const u32* p) {
    u32 v;
    asm volatile("global_load_dword %0, %1, off sc0 sc1\ns_waitcnt vmcnt(0)"
                 : "=v"(v) : "v"(p) : "memory");
    return v;
}
__device__ __forceinline__ f32x4 load_f32x4_cc_async(const void* p) {
    f32x4 v;
    asm volatile("global_load_dwordx4 %0, %1, off sc0 sc1" : "=v"(v) : "v"(p));
    return v;
}
__device__ __forceinline__ void store_u64_cc(void* p, u64 v) {
    asm volatile("global_store_dwordx2 %0, %1, off sc0 sc1" :: "v"(p), "v"(v) : "memory");
}
__device__ __forceinline__ void store_u32_cc(void* p, u32 v) {
    asm volatile("global_store_dword %0, %1, off sc0 sc1" :: "v"(p), "v"(v) : "memory");
}
__device__ __forceinline__ void wait_vm0() {
    asm volatile("s_waitcnt vmcnt(0)" ::: "memory");
}

__global__ __launch_bounds__(512, 2) void lstm_persist(
    const float* __restrict__ x,     const float* __restrict__ w_ih,
    const float* __restrict__ w_hh,  const float* __restrict__ b_ih,
    const float* __restrict__ b_hh,  const float* __restrict__ w_lin,
    const float* __restrict__ b_lin, float* __restrict__ out,
    u32* flags, char* hbase)
{
    __shared__ __align__(16) char stageBuf[40960];   // hi | lo | fp8, linear
    __shared__ float gate_s[4][16][68];              // 16B-aligned float4 rows
    __shared__ float wb_s[4][64][2];                 // {w_ih, b_ih+b_hh}
    __shared__ float xall[T_STEPS * 16];             // x staged once (32 KB)

    half8* ldsAhi = (half8*)stageBuf;
    half8* ldsAlo = (half8*)(stageBuf + 16384);
    long*  ldsA8  = (long*)(stageBuf + 32768);

    const int tid = threadIdx.x;
    const int bid = blockIdx.x;
    const int g   = bid & 15;
    const int j   = bid >> 4;
    const int U0  = j * 64;
    const int m0  = g * 16;

    const int wave = tid >> 6, lane = tid & 63;
    const int kg   = lane >> 4, l15 = lane & 15;
    const int gw   = wave >> 1;
    const int usub = (wave & 1) * 32;

    // ---- one-time: W_hh slice -> registers (fp16 hi + fp8 residual) ----
    half8 bw0[16], bw1[16];
    long  b80[16], b81[16];
    {
        const int col0 = gw * 512 + U0 + usub + l15;
        const int col1 = col0 + 16;
#pragma unroll
        for (int ks = 0; ks < 16; ++ks) {
            const float* p0 = w_hh + col0 * 512 + ks * 32 + kg * 8;
            const float* p1 = w_hh + col1 * 512 + ks * 32 + kg * 8;
            float v0[8], v1[8];
            *(float4*)(v0)     = *(const float4*)p0;
            *(float4*)(v0 + 4) = *(const float4*)(p0 + 4);
            *(float4*)(v1)     = *(const float4*)p1;
            *(float4*)(v1 + 4) = *(const float4*)(p1 + 4);
            half8 w0h, w1h; float r0[8], r1[8];
#pragma unroll
            for (int q = 0; q < 8; ++q) {
                half_t a = (half_t)v0[q]; w0h[q] = a; r0[q] = (v0[q] - (float)a) * F8_SCALE;
                half_t b = (half_t)v1[q]; w1h[q] = b; r1[q] = (v1[q] - (float)b) * F8_SCALE;
            }
            bw0[ks] = w0h; bw1[ks] = w1h;
            int lo = __builtin_amdgcn_cvt_pk_fp8_f32(r0[0], r0[1], 0, false);
            lo     = __builtin_amdgcn_cvt_pk_fp8_f32(r0[2], r0[3], lo, true);
            int hi = __builtin_amdgcn_cvt_pk_fp8_f32(r0[4], r0[5], 0, false);
            hi     = __builtin_amdgcn_cvt_pk_fp8_f32(r0[6], r0[7], hi, true);
            b80[ks] = (long)(u32)lo | ((long)hi << 32);
            lo = __builtin_amdgcn_cvt_pk_fp8_f32(r1[0], r1[1], 0, false);
            lo = __builtin_amdgcn_cvt_pk_fp8_f32(r1[2], r1[3], lo, true);
            hi = __builtin_amdgcn_cvt_pk_fp8_f32(r1[4], r1[5], 0, false);
            hi = __builtin_amdgcn_cvt_pk_fp8_f32(r1[6], r1[7], hi, true);
            b81[ks] = (long)(u32)lo | ((long)hi << 32);
        }
    }

    // ---- one-time: constants + x -> LDS ----
    if (tid < 256) {
        int gg = tid >> 6, ul = tid & 63;
        int col = gg * 512 + U0 + ul;
        wb_s[gg][ul][0] = w_ih[col];
        wb_s[gg][ul][1] = b_ih[col] + b_hh[col];
    }
    for (int i = tid; i < T_STEPS * 16; i += 512)
        xall[i] = x[(i >> 4) * 256 + m0 + (i & 15)];

    u32* gflags = flags + g * 32;

    // ---- pointwise ownership: tid<256, 4 hidden units each ----
    const int pm  = tid >> 4;          // local batch row 0..15
    const int pu4 = (tid & 15) * 4;    // hidden unit base 0..60
    const int kbg = j * 8 + (pu4 >> 3);
    const int off_hi = kbg * 256 + pm * 16 + (pu4 & 7) * 2;  // u64-aligned
    const int off_8  = kbg * 128 + pm * 8  + (pu4 & 7);      // u32-aligned
    float c4[4] = {0.f, 0.f, 0.f, 0.f};
    float h4[4] = {0.f, 0.f, 0.f, 0.f};

    // ---- startup: zero buf[1] (h_{-1}=0), publish gen 1 ----
    {
        char* z = hbase + (g * 2 + 1) * HBUF_STRIDE;
#pragma unroll
        for (int r = 0; r < 10; ++r)
            store_u64_cc(z + (r * 512 + tid) * 8, 0ull);
    }
    wait_vm0();
    __syncthreads();
    if (tid == 0) store_u32_cc(&gflags[j], 1u);

    // ---- time loop ----
    for (int t = 0; t < T_STEPS; ++t) {
        const int wb = t & 1, rb = wb ^ 1;

        // 1. wait for h_{t-1} from all 8 members (bounded; MALL-fresh polls)
        if (tid < 8) {
            const u32 want = (u32)(t + 1);
            int it = 0;
            while (load_u32_cc(&gflags[tid]) < want && ++it < POLL_CAP)
                __builtin_amdgcn_s_sleep(2);
        }
        __syncthreads();

        // 2. stage h_{t-1} (40 KB) into LDS, MALL-fresh
        {
            const char* p = hbase + (g * 2 + rb) * HBUF_STRIDE + tid * 16;
            f32x4 t0 = load_f32x4_cc_async(p);
            f32x4 t1 = load_f32x4_cc_async(p + 8192);
            f32x4 t2 = load_f32x4_cc_async(p + 16384);
            f32x4 t3 = load_f32x4_cc_async(p + 24576);
            f32x4 t4 = load_f32x4_cc_async(p + 32768);
            wait_vm0();
            f32x4* dst = (f32x4*)stageBuf;
            dst[tid] = t0; dst[512 + tid] = t1; dst[1024 + tid] = t2;
            dst[1536 + tid] = t3; dst[2048 + tid] = t4;
        }
        __syncthreads();

        // 3. GEMM: 3-term split precision, B in registers, A from LDS
        f32x4 acc0 = {0.f, 0.f, 0.f, 0.f};
        f32x4 acc1 = {0.f, 0.f, 0.f, 0.f};
        f32x4 c80  = {0.f, 0.f, 0.f, 0.f};
        f32x4 c81  = {0.f, 0.f, 0.f, 0.f};
#pragma unroll
        for (int ks = 0; ks < 16; ++ks) {
            const int ai = (ks * 4 + kg) * 16 + l15;
            half8 ahi = ldsAhi[ai];
            half8 alo = ldsAlo[ai];
            long  a8  = ldsA8[ai];
            acc0 = __builtin_amdgcn_mfma_f32_16x16x32_f16(ahi, bw0[ks], acc0, 0, 0, 0);
            acc1 = __builtin_amdgcn_mfma_f32_16x16x32_f16(ahi, bw1[ks], acc1, 0, 0, 0);
            acc0 = __builtin_amdgcn_mfma_f32_16x16x32_f16(alo, bw0[ks], acc0, 0, 0, 0);
            acc1 = __builtin_amdgcn_mfma_f32_16x16x32_f16(alo, bw1[ks], acc1, 0, 0, 0);
            c80  = __builtin_amdgcn_mfma_f32_16x16x32_fp8_fp8(a8, b80[ks], c80, 0, 0, 0);
            c81  = __builtin_amdgcn_mfma_f32_16x16x32_fp8_fp8(a8, b81[ks], c81, 0, 0, 0);
        }
#pragma unroll
        for (int e = 0; e < 4; ++e) {   // D: col=lane&15, row=(lane>>4)*4+e
            gate_s[gw][kg * 4 + e][usub + l15]      = acc0[e] + c80[e] * F8_INV;
            gate_s[gw][kg * 4 + e][usub + 16 + l15] = acc1[e] + c81[e] * F8_INV;
        }
        __syncthreads();

        // 4. pointwise + publish h_t (sc0 sc1 -> MALL)
        if (tid < 256) {
            float xv = xall[t * 16 + pm];
            float sg[4][4];
#pragma unroll
            for (int gg2 = 0; gg2 < 4; ++gg2) {
                float4 a  = *(float4*)&gate_s[gg2][pm][pu4];
                float4 wA = *(float4*)&wb_s[gg2][pu4][0];
                float4 wB = *(float4*)&wb_s[gg2][pu4 + 2][0];
                sg[gg2][0] = a.x + xv * wA.x + wA.y;
                sg[gg2][1] = a.y + xv * wA.z + wA.w;
                sg[gg2][2] = a.z + xv * wB.x + wB.y;
                sg[gg2][3] = a.w + xv * wB.z + wB.w;
            }
#pragma unroll
            for (int q = 0; q < 4; ++q) {
                float ii = sigmoid_fast(sg[0][q]);
                float ff = sigmoid_fast(sg[1][q]);
                float gv = tanh_fast(sg[2][q]);
                float oo = sigmoid_fast(sg[3][q]);
                c4[q] = ff * c4[q] + ii * gv;
                h4[q] = oo * tanh_fast(c4[q]);
            }
            union { half_t h[4]; u64 u; } hiU, loU;
#pragma unroll
            for (int q = 0; q < 4; ++q) {
                half_t hh = (half_t)h4[q];
                hiU.h[q] = hh;
                loU.h[q] = (half_t)(h4[q] - (float)hh);
            }
            int f8 = __builtin_amdgcn_cvt_pk_fp8_f32(h4[0], h4[1], 0, false);
            f8     = __builtin_amdgcn_cvt_pk_fp8_f32(h4[2], h4[3], f8, true);

            char* wrb = hbase + (g * 2 + wb) * HBUF_STRIDE;
            store_u64_cc(wrb + off_hi, hiU.u);
            store_u64_cc(wrb + 16384 + off_hi, loU.u);
            store_u32_cc(wrb + 32768 + off_8, (u32)f8);
        }
        wait_vm0();          // own h stores acked at coherence point
        __syncthreads();     // all threads' stores acked
        if (tid == 0) store_u32_cc(&gflags[j], (u32)(t + 2));
    }

    // ---- output: out[b] = w_lin . h_499[b] + b_lin (h in registers) ----
    if (tid < 256) {
        float part = h4[0] * w_lin[U0 + pu4]     + h4[1] * w_lin[U0 + pu4 + 1]
                   + h4[2] * w_lin[U0 + pu4 + 2] + h4[3] * w_lin[U0 + pu4 + 3];
        part += __shfl_xor(part, 1, 64);
        part += __shfl_xor(part, 2, 64);
        part += __shfl_xor(part, 4, 64);
        part += __shfl_xor(part, 8, 64);
        if ((tid & 15) == 0) {
            float v = part;
            if (j == 0) v += b_lin[0];
            atomicAdd(out + m0 + pm, v);
        }
    }
}

extern "C" void kernel_launch(void* const* d_in, const int* in_sizes, int n_in,
                              void* d_out, int out_size, void* d_ws, size_t ws_size,
                              hipStream_t stream) {
    const float* x     = (const float*)d_in[0];
    const float* w_ih  = (const float*)d_in[1];
    const float* w_hh  = (const float*)d_in[2];
    const float* b_ih  = (const float*)d_in[3];
    const float* b_hh  = (const float*)d_in[4];
    const float* w_lin = (const float*)d_in[5];
    const float* b_lin = (const float*)d_in[6];
    float* out = (float*)d_out;

    u32*  flags = (u32*)d_ws;
    char* hbase = (char*)d_ws + 4096;

    hipMemsetAsync(d_out, 0, out_size * sizeof(float), stream);
    hipMemsetAsync(d_ws, 0, 4096, stream);

    hipLaunchKernelGGL(lstm_persist, dim3(128), dim3(512), 0, stream,
                       x, w_ih, w_hh, b_ih, b_hh, w_lin, b_lin, out, flags, hbase);
}

// Round 12
// 1861.756 us; speedup vs baseline: 1642.2483x; 1.2153x over previous
//
#include <hip/hip_runtime.h>
#include <hip/hip_fp16.h>

#define T_STEPS 500
#define HBUF_STRIDE 24576   // per (g,buf): hi 16384 | fp8 8192
#define F8_SCALE    32768.0f
#define F8_INV      3.0517578125e-05f   // 2^-15
#define POLL_CAP    4096

typedef _Float16 half_t;
typedef __attribute__((ext_vector_type(8))) _Float16 half8;
typedef __attribute__((ext_vector_type(4))) float    f32x4;
typedef unsigned int       u32;
typedef unsigned long long u64;

// Persistent LSTM, MALL-coherent exchange (sc0 sc1 on every cross-block op).
//   grid = 128 x 512. group g = bid & 15 owns batch rows [16g,16g+16);
//   j = bid >> 4 owns hidden slice U0 = j*64 (gate cols gate*512+U0+u).
//   Weights in registers: fp16 hi (128 VGPR) + fp8-e4m3 residual*2^15 (32 VGPR).
//   Exchange payload: h as fp16 hi + fp8(h) only (h_lo term dropped: ~1e-4
//   zero-mean noise, far under threshold; weight residual term KEPT -> no
//   systematic weight quantization error).
//   gates = hi(h)@W_hi + 2^-15 * (fp8(h) @ W_lo8)      [fp32 MFMA accum]
//   Per-wave poll+stage: wave w polls peer w's flag then stages its 3 KB
//   slice -> poll latency overlaps staging across peers.
// ws: flags[16][32] u32 @0 (memset 0 each call); hbuf [16][2][24576] @4096.

__device__ __forceinline__ float sigmoid_fast(float v) {
    return 1.f / (1.f + __expf(-v));
}
__device__ __forceinline__ float tanh_fast(float v) {
    float a = fabsf(v);
    float e = __expf(-2.f * a);
    float t = (1.f - e) / (1.f + e);
    return copysignf(t, v);
}

// ---- MALL-coherent ops: sc0 sc1 = bypass L1 and L2 ----
__device__ __forceinline__ u32 load_u32_cc(const u32* p) {
    u32 v;
    asm volatile("global_load_dword %0, %1, off sc0 sc1\ns_waitcnt vmcnt(0)"
                 : "=v"(v) : "v"(p) : "memory");
    return v;
}
__device__ __forceinline__ f32x4 load_f32x4_cc_async(const void* p) {
    f32x4 v;
    asm volatile("global_load_dwordx4 %0, %1, off sc0 sc1" : "=v"(v) : "v"(p));
    return v;
}
__device__ __forceinline__ void store_u64_cc(void* p, u64 v) {
    asm volatile("global_store_dwordx2 %0, %1, off sc0 sc1" :: "v"(p), "v"(v) : "memory");
}
__device__ __forceinline__ void store_u32_cc(void* p, u32 v) {
    asm volatile("global_store_dword %0, %1, off sc0 sc1" :: "v"(p), "v"(v) : "memory");
}
__device__ __forceinline__ void wait_vm0() {
    asm volatile("s_waitcnt vmcnt(0)" ::: "memory");
}

__global__ __launch_bounds__(512, 2) void lstm_persist(
    const float* __restrict__ x,     const float* __restrict__ w_ih,
    const float* __restrict__ w_hh,  const float* __restrict__ b_ih,
    const float* __restrict__ b_hh,  const float* __restrict__ w_lin,
    const float* __restrict__ b_lin, float* __restrict__ out,
    u32* flags, char* hbase)
{
    __shared__ __align__(16) char stageBuf[24576];   // hi 16K | fp8 8K
    __shared__ float gate_s[4][16][68];              // 16B-aligned float4 rows
    __shared__ float wb_s[4][64][2];                 // {w_ih, b_ih+b_hh}
    __shared__ float xall[T_STEPS * 16];             // x staged once (32 KB)

    half8* ldsAhi = (half8*)stageBuf;
    long*  ldsA8  = (long*)(stageBuf + 16384);

    const int tid = threadIdx.x;
    const int bid = blockIdx.x;
    const int g   = bid & 15;
    const int j   = bid >> 4;
    const int U0  = j * 64;
    const int m0  = g * 16;

    const int wave = tid >> 6, lane = tid & 63;
    const int kg   = lane >> 4, l15 = lane & 15;
    const int gw   = wave >> 1;
    const int usub = (wave & 1) * 32;

    // ---- one-time: W_hh slice -> registers (fp16 hi + fp8 residual) ----
    half8 bw0[16], bw1[16];
    long  b80[16], b81[16];
    {
        const int col0 = gw * 512 + U0 + usub + l15;
        const int col1 = col0 + 16;
#pragma unroll
        for (int ks = 0; ks < 16; ++ks) {
            const float* p0 = w_hh + col0 * 512 + ks * 32 + kg * 8;
            const float* p1 = w_hh + col1 * 512 + ks * 32 + kg * 8;
            float v0[8], v1[8];
            *(float4*)(v0)     = *(const float4*)p0;
            *(float4*)(v0 + 4) = *(const float4*)(p0 + 4);
            *(float4*)(v1)     = *(const float4*)p1;
            *(float4*)(v1 + 4) = *(const float4*)(p1 + 4);
            half8 w0h, w1h; float r0[8], r1[8];
#pragma unroll
            for (int q = 0; q < 8; ++q) {
                half_t a = (half_t)v0[q]; w0h[q] = a; r0[q] = (v0[q] - (float)a) * F8_SCALE;
                half_t b = (half_t)v1[q]; w1h[q] = b; r1[q] = (v1[q] - (float)b) * F8_SCALE;
            }
            bw0[ks] = w0h; bw1[ks] = w1h;
            int lo = __builtin_amdgcn_cvt_pk_fp8_f32(r0[0], r0[1], 0, false);
            lo     = __builtin_amdgcn_cvt_pk_fp8_f32(r0[2], r0[3], lo, true);
            int hi = __builtin_amdgcn_cvt_pk_fp8_f32(r0[4], r0[5], 0, false);
            hi     = __builtin_amdgcn_cvt_pk_fp8_f32(r0[6], r0[7], hi, true);
            b80[ks] = (long)(u32)lo | ((long)hi << 32);
            lo = __builtin_amdgcn_cvt_pk_fp8_f32(r1[0], r1[1], 0, false);
            lo = __builtin_amdgcn_cvt_pk_fp8_f32(r1[2], r1[3], lo, true);
            hi = __builtin_amdgcn_cvt_pk_fp8_f32(r1[4], r1[5], 0, false);
            hi = __builtin_amdgcn_cvt_pk_fp8_f32(r1[6], r1[7], hi, true);
            b81[ks] = (long)(u32)lo | ((long)hi << 32);
        }
    }

    // ---- one-time: constants + x -> LDS ----
    if (tid < 256) {
        int gg = tid >> 6, ul = tid & 63;
        int col = gg * 512 + U0 + ul;
        wb_s[gg][ul][0] = w_ih[col];
        wb_s[gg][ul][1] = b_ih[col] + b_hh[col];
    }
    for (int i = tid; i < T_STEPS * 16; i += 512)
        xall[i] = x[(i >> 4) * 256 + m0 + (i & 15)];

    u32* gflags = flags + g * 32;

    // ---- pointwise ownership: tid<256, 4 hidden units each ----
    const int pm  = tid >> 4;          // local batch row 0..15
    const int pu4 = (tid & 15) * 4;    // hidden unit base 0..60
    const int kbg = j * 8 + (pu4 >> 3);
    const int off_hi = kbg * 256 + pm * 16 + (pu4 & 7) * 2;  // u64-aligned
    const int off_8  = kbg * 128 + pm * 8  + (pu4 & 7);      // u32-aligned
    float c4[4] = {0.f, 0.f, 0.f, 0.f};
    float h4[4] = {0.f, 0.f, 0.f, 0.f};

    // ---- startup: zero buf[1] (h_{-1}=0), publish gen 1 ----
    {
        char* z = hbase + (g * 2 + 1) * HBUF_STRIDE;
#pragma unroll
        for (int r = 0; r < 6; ++r)
            store_u64_cc(z + (r * 512 + tid) * 8, 0ull);
    }
    wait_vm0();
    __syncthreads();
    if (tid == 0) store_u32_cc(&gflags[j], 1u);

    // ---- time loop ----
    for (int t = 0; t < T_STEPS; ++t) {
        const int wb = t & 1, rb = wb ^ 1;
        const char* src = hbase + (g * 2 + rb) * HBUF_STRIDE;

        // 1+2. per-wave: poll peer `wave`'s flag, then stage its 3 KB slice
        //      (hi: 2 KB at wave*2048; fp8: 1 KB at 16384 + wave*1024)
        {
            const u32 want = (u32)(t + 1);
            int it = 0;
            while (load_u32_cc(&gflags[wave]) < want && ++it < POLL_CAP) {}
            const int hoff = wave * 2048 + lane * 16;
            const int foff = 16384 + wave * 1024 + lane * 16;
            f32x4 t0 = load_f32x4_cc_async(src + hoff);
            f32x4 t1 = load_f32x4_cc_async(src + hoff + 1024);
            f32x4 t2 = load_f32x4_cc_async(src + foff);
            wait_vm0();
            *(f32x4*)(stageBuf + hoff)        = t0;
            *(f32x4*)(stageBuf + hoff + 1024) = t1;
            *(f32x4*)(stageBuf + foff)        = t2;
        }
        __syncthreads();

        // 3. GEMM: 2-term split precision, B in registers, A from LDS
        f32x4 acc0 = {0.f, 0.f, 0.f, 0.f};
        f32x4 acc1 = {0.f, 0.f, 0.f, 0.f};
        f32x4 c80  = {0.f, 0.f, 0.f, 0.f};
        f32x4 c81  = {0.f, 0.f, 0.f, 0.f};
#pragma unroll
        for (int ks = 0; ks < 16; ++ks) {
            const int ai = (ks * 4 + kg) * 16 + l15;
            half8 ahi = ldsAhi[ai];
            long  a8  = ldsA8[ai];
            acc0 = __builtin_amdgcn_mfma_f32_16x16x32_f16(ahi, bw0[ks], acc0, 0, 0, 0);
            acc1 = __builtin_amdgcn_mfma_f32_16x16x32_f16(ahi, bw1[ks], acc1, 0, 0, 0);
            c80  = __builtin_amdgcn_mfma_f32_16x16x32_fp8_fp8(a8, b80[ks], c80, 0, 0, 0);
            c81  = __builtin_amdgcn_mfma_f32_16x16x32_fp8_fp8(a8, b81[ks], c81, 0, 0, 0);
        }
#pragma unroll
        for (int e = 0; e < 4; ++e) {   // D: col=lane&15, row=(lane>>4)*4+e
            gate_s[gw][kg * 4 + e][usub + l15]      = acc0[e] + c80[e] * F8_INV;
            gate_s[gw][kg * 4 + e][usub + 16 + l15] = acc1[e] + c81[e] * F8_INV;
        }
        __syncthreads();

        // 4. pointwise + publish h_t (sc0 sc1 -> MALL)
        if (tid < 256) {
            float xv = xall[t * 16 + pm];
            float sg[4][4];
#pragma unroll
            for (int gg2 = 0; gg2 < 4; ++gg2) {
                float4 a  = *(float4*)&gate_s[gg2][pm][pu4];
                float4 wA = *(float4*)&wb_s[gg2][pu4][0];
                float4 wB = *(float4*)&wb_s[gg2][pu4 + 2][0];
                sg[gg2][0] = a.x + xv * wA.x + wA.y;
                sg[gg2][1] = a.y + xv * wA.z + wA.w;
                sg[gg2][2] = a.z + xv * wB.x + wB.y;
                sg[gg2][3] = a.w + xv * wB.z + wB.w;
            }
#pragma unroll
            for (int q = 0; q < 4; ++q) {
                float ii = sigmoid_fast(sg[0][q]);
                float ff = sigmoid_fast(sg[1][q]);
                float gv = tanh_fast(sg[2][q]);
                float oo = sigmoid_fast(sg[3][q]);
                c4[q] = ff * c4[q] + ii * gv;
                h4[q] = oo * tanh_fast(c4[q]);
            }
            union { half_t h[4]; u64 u; } hiU;
#pragma unroll
            for (int q = 0; q < 4; ++q) hiU.h[q] = (half_t)h4[q];
            int f8 = __builtin_amdgcn_cvt_pk_fp8_f32(h4[0], h4[1], 0, false);
            f8     = __builtin_amdgcn_cvt_pk_fp8_f32(h4[2], h4[3], f8, true);

            char* wrb = hbase + (g * 2 + wb) * HBUF_STRIDE;
            store_u64_cc(wrb + off_hi, hiU.u);
            store_u32_cc(wrb + 16384 + off_8, (u32)f8);
        }
        wait_vm0();          // own h stores acked at coherence point
        __syncthreads();     // all threads' stores acked
        if (tid == 0) store_u32_cc(&gflags[j], (u32)(t + 2));
    }

    // ---- output: out[b] = w_lin . h_499[b] + b_lin (h in registers) ----
    if (tid < 256) {
        float part = h4[0] * w_lin[U0 + pu4]     + h4[1] * w_lin[U0 + pu4 + 1]
                   + h4[2] * w_lin[U0 + pu4 + 2] + h4[3] * w_lin[U0 + pu4 + 3];
        part += __shfl_xor(part, 1, 64);
        part += __shfl_xor(part, 2, 64);
        part += __shfl_xor(part, 4, 64);
        part += __shfl_xor(part, 8, 64);
        if ((tid & 15) == 0) {
            float v = part;
            if (j == 0) v += b_lin[0];
            atomicAdd(out + m0 + pm, v);
        }
    }
}

extern "C" void kernel_launch(void* const* d_in, const int* in_sizes, int n_in,
                              void* d_out, int out_size, void* d_ws, size_t ws_size,
                              hipStream_t stream) {
    const float* x     = (const float*)d_in[0];
    const float* w_ih  = (const float*)d_in[1];
    const float* w_hh  = (const float*)d_in[2];
    const float* b_ih  = (const float*)d_in[3];
    const float* b_hh  = (const float*)d_in[4];
    const float* w_lin = (const float*)d_in[5];
    const float* b_lin = (const float*)d_in[6];
    float* out = (float*)d_out;

    u32*  flags = (u32*)d_ws;
    char* hbase = (char*)d_ws + 4096;

    hipMemsetAsync(d_out, 0, out_size * sizeof(float), stream);
    hipMemsetAsync(d_ws, 0, 4096, stream);

    hipLaunchKernelGGL(lstm_persist, dim3(128), dim3(512), 0, stream,
                       x, w_ih, w_hh, b_ih, b_hh, w_lin, b_lin, out, flags, hbase);
}